// Round 11
// baseline (149.716 us; speedup 1.0000x reference)
//
#include <hip/hip_runtime.h>

typedef __bf16 bf16x8 __attribute__((ext_vector_type(8)));
typedef float f32x4 __attribute__((ext_vector_type(4)));

__device__ __forceinline__ unsigned short f2b(float f) {
    union { float f; unsigned u; } c; c.f = f;
    unsigned u = c.u;
    return (unsigned short)((u + 0x7FFFu + ((u >> 16) & 1u)) >> 16);
}

__device__ __forceinline__ unsigned pack2(float v0, float v1) {
    union { __bf16 h[2]; unsigned u; } c;
    c.h[0] = (__bf16)v0; c.h[1] = (__bf16)v1;
    return c.u;
}

// Direct global->LDS DMA, 16 B per lane. LDS dest is wave-uniform base + lane*16;
// global src is per-lane.
__device__ __forceinline__ void gload_lds16(const unsigned short* g, unsigned short* l) {
    __builtin_amdgcn_global_load_lds(
        (__attribute__((address_space(1))) unsigned int*)(g),
        (__attribute__((address_space(3))) unsigned int*)(l), 16, 0, 0);
}

// Stage one 24-frag (24 KiB) page into LDS: exactly 6 global_load_lds per wave,
// uniform across waves -> a wave-uniform counted vmcnt(6) is legal.
__device__ __forceinline__ void stage_page(const unsigned short* __restrict__ g,
                                           unsigned short* l, int wid, int lane)
{
#pragma unroll
    for (int k = 0; k < 6; ++k) {
        const int idx = wid + k * 4;
        gload_lds16(g + idx * 512 + lane * 8, l + idx * 512);
    }
}

// Triangular entry decode: e in [0, 9216) -> (b, i, j0, offdiag) with j0/32 >= i/32.
__device__ __forceinline__ void decode_entry(int e, int& b, int& i, int& j0, bool& offdiag)
{
    b = e / 1152;
    const int r = e - b * 1152;
    const int tp = r >> 5;                      // tile-pair 0..35 (upper tri of 8x8)
    const int row_in = r & 31;
    int rg = 0, tt = tp;
#pragma unroll 8
    for (;;) { int cnt = 8 - rg; if (tt < cnt) break; tt -= cnt; ++rg; }
    const int cg = rg + tt;
    i = rg * 32 + row_in;
    j0 = cg * 32;
    offdiag = (cg != rg);
}

// Build layer-0 B-frags: B0[t][s] holds |x_i - x_j| transposed (k=fin, col=pos).
// Lane (cl,g): elem e = h0[pos=16t+cl][f=32s+8g+e]; frags fully valid or fully zero
// (CIN multiple of 8).
template<int CIN, int KN0>
__device__ __forceinline__ void build_frags0(const float* __restrict__ xi,
    const float* __restrict__ xj, int cl, int g, bf16x8 (&B0)[2][6])
{
#pragma unroll
    for (int s = 0; s < KN0; ++s) {
        const int f0 = s * 32 + 8 * g;
        const bool valid = f0 < CIN;
        f32x4 xa = {0.f,0.f,0.f,0.f}, xb = {0.f,0.f,0.f,0.f};
        if (valid) { xa = *(const f32x4*)(xi + f0); xb = *(const f32x4*)(xi + f0 + 4); }
#pragma unroll
        for (int t = 0; t < 2; ++t) {
            bf16x8 r;
            if (valid) {
                const float* pj = xj + (16 * t + cl) * CIN + f0;
                f32x4 ja = *(const f32x4*)pj, jb = *(const f32x4*)(pj + 4);
#pragma unroll
                for (int e = 0; e < 4; ++e) {
                    r[e]     = (__bf16)fabsf(xa[e] - ja[e]);
                    r[e + 4] = (__bf16)fabsf(xb[e] - jb[e]);
                }
            } else {
#pragma unroll
                for (int e = 0; e < 8; ++e) r[e] = (__bf16)0.f;
            }
            B0[t][s] = r;
        }
    }
}

// One c-pair (32 output channels x full K) from LDS. Bias is DEFERRED: acc
// zero-init, bias loads issued up front, consumed only in the epilogue -- the
// MFMA loop covers their L2 latency. T5: the ds_read+MFMA cluster runs at
// s_setprio(1) so the CU scheduler favors MFMA-window waves over waves doing
// staging/epilogue (pays in phase-split counted-vmcnt schedules, m218b).
// Shuffle-free repack: next-layer frag CP takes channels from acc tiles
// a=2CP,2CP+1 resident in the SAME lane (tau-permuted downstream weights).
template<int KN, int CP>
__device__ __forceinline__ void run_cpair(const unsigned short* wlds,
    const float* __restrict__ bias, const bf16x8 (&Bc)[2][6], bf16x8 (&Bn)[2][6],
    int lane, int g)
{
    f32x4 bv0 = *(const f32x4*)&bias[(2 * CP + 0) * 16 + 4 * g];
    f32x4 bv1 = *(const f32x4*)&bias[(2 * CP + 1) * 16 + 4 * g];
    f32x4 acc[2][2];                       // [cc][t]
#pragma unroll
    for (int cc = 0; cc < 2; ++cc)
#pragma unroll
        for (int t = 0; t < 2; ++t)
            acc[cc][t] = f32x4{0.f, 0.f, 0.f, 0.f};
    __builtin_amdgcn_s_setprio(1);
#pragma unroll
    for (int s = 0; s < KN; ++s) {
#pragma unroll
        for (int cc = 0; cc < 2; ++cc) {
            bf16x8 w = *(const bf16x8*)&wlds[((cc * KN + s) * 64 + lane) * 8];
#pragma unroll
            for (int t = 0; t < 2; ++t)
                acc[cc][t] = __builtin_amdgcn_mfma_f32_16x16x32_bf16(w, Bc[t][s], acc[cc][t], 0, 0, 0);
        }
    }
    __builtin_amdgcn_s_setprio(0);
#pragma unroll
    for (int t = 0; t < 2; ++t) {
        union { unsigned w[4]; bf16x8 v; } outv;
#pragma unroll
        for (int cc = 0; cc < 2; ++cc) {
            const f32x4 bv = cc ? bv1 : bv0;
#pragma unroll
            for (int m = 0; m < 2; ++m) {
                float v0 = acc[cc][t][2 * m] + bv[2 * m];
                float v1 = acc[cc][t][2 * m + 1] + bv[2 * m + 1];
                v0 = fmaxf(v0, 0.01f * v0);      // LeakyReLU(0.01)
                v1 = fmaxf(v1, 0.01f * v1);
                outv.w[cc * 2 + m] = pack2(v0, v1);
            }
        }
        Bn[t][CP] = outv.v;
    }
}

// adj0 L0: 6 c-pairs of KN=1 (c-pair = 1024 elems) from one half-page base.
__device__ __forceinline__ void compute_l0_kn1(const unsigned short* cur,
    const float* __restrict__ b0, const bf16x8 (&Ba)[2][6], bf16x8 (&Bb)[2][6],
    int lane, int g)
{
    run_cpair<1, 0>(cur,        b0, Ba, Bb, lane, g);
    run_cpair<1, 1>(cur + 1024, b0, Ba, Bb, lane, g);
    run_cpair<1, 2>(cur + 2048, b0, Ba, Bb, lane, g);
    run_cpair<1, 3>(cur + 3072, b0, Ba, Bb, lane, g);
    run_cpair<1, 4>(cur + 4096, b0, Ba, Bb, lane, g);
    run_cpair<1, 5>(cur + 5120, b0, Ba, Bb, lane, g);
}

// adj1 L0 pair P2: 2 c-pairs of KN=3 (c-pair = 3072 elems) from a 6144-elem base.
template<int P2>
__device__ __forceinline__ void compute_l0_kn3(const unsigned short* cur,
    const float* __restrict__ b0, const bf16x8 (&Ba)[2][6], bf16x8 (&Bb)[2][6],
    int lane, int g)
{
    run_cpair<3, 2 * P2>    (cur,        b0, Ba, Bb, lane, g);
    run_cpair<3, 2 * P2 + 1>(cur + 3072, b0, Ba, Bb, lane, g);
}

// Counted-vmcnt pipelined phase (T4 pattern, race-free), 24 KiB pages:
//  stage(page p+1)                 -- 6 loads, stay IN FLIGHT under compute
//  vmcnt(6)+barrier                -- page p landed for ALL waves (own 6 allowed out)
//  compute(page p)                 -- 2 c-pairs: 24 ds_read + 48 MFMA window
//  lgkmcnt(0)+barrier              -- all reads of the other buffer done -> reusable
// No vmcnt(0) drain in the steady loop.
#define PH(OFF, ...) \
    stage_page(wchain + (OFF), nxt, wid, lane); \
    asm volatile("s_waitcnt vmcnt(6)\n\ts_barrier" ::: "memory"); \
    __VA_ARGS__; \
    asm volatile("s_waitcnt lgkmcnt(0)\n\ts_barrier" ::: "memory"); \
    { unsigned short* t_ = cur; cur = nxt; nxt = t_; }

#define PHLAST(...) \
    asm volatile("s_waitcnt vmcnt(0)\n\ts_barrier" ::: "memory"); \
    __VA_ARGS__;

// Fused adjacency MLP exploiting logit symmetry (upper-triangle 32x32 j-tiles,
// off-diagonal entries mirror-write logits[j][i]). Block = 256 threads = 4 waves,
// wave owns ONE entry. Weight chains consumed as uniform 24 KiB pages (adj0: 8,
// adj1: 9), double-buffered (2 x 24 KiB LDS), counted-vmcnt pipeline + T5 setprio.
// (256,3): cap 170 unified regs fits (R8-R10: no spill), 3 blocks/CU = 12 waves/CU.
// Grid 2304 = 256 CU x 3 x 3 rounds, zero tail.
template<int CIN, int KN0>
__global__ __launch_bounds__(256, 3)
void adj_mlp_kernel(const float* __restrict__ src,
                    const unsigned short* __restrict__ wchain,
                    const unsigned short* __restrict__ w4f,
                    const float* __restrict__ b0, const float* __restrict__ b1,
                    const float* __restrict__ b2, const float* __restrict__ b3,
                    const float* __restrict__ b4,
                    float* __restrict__ logits)
{
    __shared__ unsigned short wbuf0[12288], wbuf1[12288];   // 2 x 24 KiB page buffers
    const int tid = threadIdx.x;
    const int wid = tid >> 6, lane = tid & 63;
    const int cl = lane & 15, g = lane >> 4;

    int b, i, j0; bool offdiag;
    decode_entry(blockIdx.x * 4 + wid, b, i, j0, offdiag);

    const float* xi = src + (b * 256 + i) * CIN;
    const float* xj = src + (b * 256 + j0) * CIN;

    // Prologue: stage page 0; build input frags under the staging latency.
    stage_page(wchain, wbuf0, wid, lane);

    bf16x8 Ba[2][6], Bb[2][6];
    build_frags0<CIN, KN0>(xi, xj, cl, g, Ba);
    unsigned short* cur = wbuf0;
    unsigned short* nxt = wbuf1;

    if constexpr (KN0 == 1) {
        // adj0: 8 pages of 12288 elems over [L0 x6cp KN=1][L1 cp0..5][L2 cp0..5][L3 cp0..2]
        PH(1 * 12288, { compute_l0_kn1(cur, b0, Ba, Bb, lane, g);
                        run_cpair<6, 0>(cur + 6144, b1, Bb, Ba, lane, g); })
        PH(2 * 12288, { run_cpair<6, 1>(cur, b1, Bb, Ba, lane, g);
                        run_cpair<6, 2>(cur + 6144, b1, Bb, Ba, lane, g); })
        PH(3 * 12288, { run_cpair<6, 3>(cur, b1, Bb, Ba, lane, g);
                        run_cpair<6, 4>(cur + 6144, b1, Bb, Ba, lane, g); })
        PH(4 * 12288, { run_cpair<6, 5>(cur, b1, Bb, Ba, lane, g);
                        run_cpair<6, 0>(cur + 6144, b2, Ba, Bb, lane, g); })
        PH(5 * 12288, { run_cpair<6, 1>(cur, b2, Ba, Bb, lane, g);
                        run_cpair<6, 2>(cur + 6144, b2, Ba, Bb, lane, g); })
        PH(6 * 12288, { run_cpair<6, 3>(cur, b2, Ba, Bb, lane, g);
                        run_cpair<6, 4>(cur + 6144, b2, Ba, Bb, lane, g); })
        PH(7 * 12288, { run_cpair<6, 5>(cur, b2, Ba, Bb, lane, g);
                        run_cpair<6, 0>(cur + 6144, b3, Bb, Ba, lane, g); })
        PHLAST({ run_cpair<6, 1>(cur, b3, Bb, Ba, lane, g);
                 run_cpair<6, 2>(cur + 6144, b3, Bb, Ba, lane, g); })
    } else {
        // adj1: 9 pages of 12288 elems over [L0 x6cp KN=3][L1 cp0..5][L2 cp0..5][L3 cp0..2]
        PH(1 * 12288, { compute_l0_kn3<0>(cur, b0, Ba, Bb, lane, g);
                        compute_l0_kn3<1>(cur + 6144, b0, Ba, Bb, lane, g); })
        PH(2 * 12288, { compute_l0_kn3<2>(cur, b0, Ba, Bb, lane, g);
                        run_cpair<6, 0>(cur + 6144, b1, Bb, Ba, lane, g); })
        PH(3 * 12288, { run_cpair<6, 1>(cur, b1, Bb, Ba, lane, g);
                        run_cpair<6, 2>(cur + 6144, b1, Bb, Ba, lane, g); })
        PH(4 * 12288, { run_cpair<6, 3>(cur, b1, Bb, Ba, lane, g);
                        run_cpair<6, 4>(cur + 6144, b1, Bb, Ba, lane, g); })
        PH(5 * 12288, { run_cpair<6, 5>(cur, b1, Bb, Ba, lane, g);
                        run_cpair<6, 0>(cur + 6144, b2, Ba, Bb, lane, g); })
        PH(6 * 12288, { run_cpair<6, 1>(cur, b2, Ba, Bb, lane, g);
                        run_cpair<6, 2>(cur + 6144, b2, Ba, Bb, lane, g); })
        PH(7 * 12288, { run_cpair<6, 3>(cur, b2, Ba, Bb, lane, g);
                        run_cpair<6, 4>(cur + 6144, b2, Ba, Bb, lane, g); })
        PH(8 * 12288, { run_cpair<6, 5>(cur, b2, Ba, Bb, lane, g);
                        run_cpair<6, 0>(cur + 6144, b3, Bb, Ba, lane, g); })
        PHLAST({ run_cpair<6, 1>(cur, b3, Bb, Ba, lane, g);
                 run_cpair<6, 2>(cur + 6144, b3, Bb, Ba, lane, g); })
    }

    // final 96 -> 1: tiny w4 stays in global (L2-hit, 6 loads/wave)
    const float bv4 = b4[0];
#pragma unroll
    for (int t = 0; t < 2; ++t) {
        f32x4 acc = {bv4, bv4, bv4, bv4};
#pragma unroll
        for (int s = 0; s < 3; ++s) {
            bf16x8 w = *(const bf16x8*)(w4f + (s * 64 + lane) * 8);
            acc = __builtin_amdgcn_mfma_f32_16x16x32_bf16(w, Ba[t][s], acc, 0, 0, 0);
        }
        if (g == 0) {
            int j = j0 + 16 * t + cl;
            float lg = acc[0];
            if (j == i) lg -= 1e8f;
            logits[(b * 256 + i) * 256 + j] = lg;
            if (offdiag)
                logits[(b * 256 + j) * 256 + i] = lg;    // symmetric mirror (i != j)
        }
    }
}

// Pre-pack weight matrices (bf16). Same lane<->element map serves A- and B-frags.
// Layers 0-7: conv chains (a0 then a1). Layers 8-9: w4 vectors in row/col 0.
// Layers whose INPUT comes from a previous MFMA layer (1,2,3, 5,6,7, 8,9) use the
// shuffle-free k-permutation tau(s,g,e) = 32s + 16*(e>>2) + 4g + (e&3); layers fed
// by build_frags0 (0, 4) keep the natural order k = 32s + 8g + e.
struct PackPtrs { const float* w[10]; };

__global__ void pack_kernel(PackPtrs pp, unsigned short* __restrict__ dst)
{
    const int K_[10]   = {24, 192, 192, 192, 72, 192, 192, 192, 96, 96};
    const int KN_[10]  = {1, 6, 6, 6, 3, 6, 6, 6, 3, 3};
    const int NO_[10]  = {192, 192, 192, 96, 192, 192, 192, 96, 1, 1};
    const int OFF_[10] = {0, 6144, 43008, 79872, 98304, 116736, 153600, 190464, 208896, 210432};
    const int LEN_[10] = {6144, 36864, 36864, 18432, 18432, 36864, 36864, 18432, 1536, 1536};
    int t = blockIdx.x * 256 + threadIdx.x;   // total threads == 211968 exactly
    int layer = 0, base = 0;
#pragma unroll
    for (int L = 0; L < 10; ++L)
        if (t >= base + LEN_[L]) { base += LEN_[L]; layer = L + 1; }
    if (layer >= 10) return;
    int u = t - base;
    int e = u & 7;
    int lane = (u >> 3) & 63;
    int gg = lane >> 4;
    int KN = KN_[layer];
    int fi = u >> 9;              // frag index = c*KN + s
    int s = fi % KN;
    int c = fi / KN;
    int k;
    if (layer == 0 || layer == 4)
        k = s * 32 + gg * 8 + e;                              // natural (build_frags0 input)
    else
        k = s * 32 + ((e >> 2) << 4) + (gg << 2) + (e & 3);   // tau (MFMA-output input)
    int col = (c << 4) + (lane & 15);
    float v = 0.f;
    if (layer < 8) {
        if (k < K_[layer]) v = pp.w[layer][k * NO_[layer] + col];
    } else {
        if ((lane & 15) == 0) v = pp.w[layer][k];   // k < 96 always
    }
    dst[OFF_[layer] + u] = f2b(v);
}

// Row softmax (in-place on the a-region in d_out) + fused agg[f] = sum_j p[j]*src[b,j,f]
template<int F>
__global__ __launch_bounds__(256)
void softmax_agg_kernel(float* __restrict__ amat, const float* __restrict__ src,
                        float* __restrict__ agg)
{
    __shared__ float pl[256];
    __shared__ float redm[4], reds[4];
    const int row = blockIdx.x;     // b*256 + i
    const int b = row >> 8;
    float* arow = amat + row * 256;
    const int t = threadIdx.x;
    const int lane = t & 63, wid = t >> 6;
    float v = arow[t];
    float m = v;
#pragma unroll
    for (int off = 32; off; off >>= 1) m = fmaxf(m, __shfl_xor(m, off));
    if (lane == 0) redm[wid] = m;
    __syncthreads();
    m = fmaxf(fmaxf(redm[0], redm[1]), fmaxf(redm[2], redm[3]));
    float e = __expf(v - m);
    float sum = e;
#pragma unroll
    for (int off = 32; off; off >>= 1) sum += __shfl_xor(sum, off);
    if (lane == 0) reds[wid] = sum;
    __syncthreads();
    sum = reds[0] + reds[1] + reds[2] + reds[3];
    float p = e / sum;
    arow[t] = p;
    pl[t] = p;
    __syncthreads();
    if (t < F) {
        const float* sb = src + (b * 256) * F + t;
        float acc = 0.f;
#pragma unroll 8
        for (int j = 0; j < 256; ++j)
            acc += pl[j] * sb[j * F];
        agg[row * F + t] = acc;
    }
}

// x1 = leaky([x | agg0] @ g0_w^T + g0_b); xc = [x | x1]
__global__ __launch_bounds__(64)
void graph0_kernel(const float* __restrict__ x, const float* __restrict__ agg0,
                   const float* __restrict__ w, const float* __restrict__ bias,
                   float* __restrict__ xc)
{
    int row = blockIdx.x;
    int t = threadIdx.x;
    const float* xr = x + row * 24;
    const float* ar = agg0 + row * 24;
    if (t < 24) xc[row * 72 + t] = xr[t];
    if (t < 48) {
        float acc = bias[t];
#pragma unroll
        for (int f = 0; f < 24; ++f) acc += xr[f] * w[t * 48 + f];
#pragma unroll
        for (int f = 0; f < 24; ++f) acc += ar[f] * w[t * 48 + 24 + f];
        acc = acc >= 0.f ? acc : 0.01f * acc;
        xc[row * 72 + 24 + t] = acc;
    }
}

// out = [xc | agg1] @ g1_w^T + g1_b   (no activation)
__global__ __launch_bounds__(64)
void graph1_kernel(const float* __restrict__ xc, const float* __restrict__ agg1,
                   const float* __restrict__ w, const float* __restrict__ bias,
                   float* __restrict__ out)
{
    int row = blockIdx.x;
    int t = threadIdx.x;
    float acc = 0.f;
    for (int idx = t; idx < 144; idx += 64) {
        float v = (idx < 72) ? xc[row * 72 + idx] : agg1[row * 72 + idx - 72];
        acc += v * w[idx];
    }
#pragma unroll
    for (int off = 32; off >= 1; off >>= 1) acc += __shfl_xor(acc, off);
    if (t == 0) out[row] = acc + bias[0];
}

extern "C" void kernel_launch(void* const* d_in, const int* in_sizes, int n_in,
                              void* d_out, int out_size, void* d_ws, size_t ws_size,
                              hipStream_t stream)
{
    const float* x = (const float*)d_in[0];
    float* out = (float*)d_out;
    float* a0 = out + 2048;
    float* a1 = a0 + 524288;

    char* ws = (char*)d_ws;
    unsigned short* packed = (unsigned short*)ws;          // 211968 bf16 = 423,936 B
    float* xc   = (float*)(ws + 458752);                   // [2048][72] f32
    float* agg0 = (float*)(ws + 1048576);                  // [2048][24] f32
    float* agg1 = (float*)(ws + 1245184);                  // [2048][72] f32

    PackPtrs pp;
    pp.w[0] = (const float*)d_in[1];   // a0_w0 [24,192]
    pp.w[1] = (const float*)d_in[3];   // a0_w1 [192,192]
    pp.w[2] = (const float*)d_in[5];   // a0_w2
    pp.w[3] = (const float*)d_in[7];   // a0_w3 [192,96]
    pp.w[4] = (const float*)d_in[11];  // a1_w0 [72,192]
    pp.w[5] = (const float*)d_in[13];  // a1_w1
    pp.w[6] = (const float*)d_in[15];  // a1_w2
    pp.w[7] = (const float*)d_in[17];  // a1_w3
    pp.w[8] = (const float*)d_in[9];   // a0_w4 [96,1]
    pp.w[9] = (const float*)d_in[19];  // a1_w4 [96,1]
    pack_kernel<<<828, 256, 0, stream>>>(pp, packed);      // 828*256 == 211968

    adj_mlp_kernel<24, 1><<<2304, 256, 0, stream>>>(
        x, packed, packed + 208896,
        (const float*)d_in[2], (const float*)d_in[4], (const float*)d_in[6],
        (const float*)d_in[8], (const float*)d_in[10], a0);

    softmax_agg_kernel<24><<<2048, 256, 0, stream>>>(a0, x, agg0);

    graph0_kernel<<<2048, 64, 0, stream>>>(x, agg0,
        (const float*)d_in[21], (const float*)d_in[22], xc);

    adj_mlp_kernel<72, 3><<<2304, 256, 0, stream>>>(
        xc, packed + 98304, packed + 210432,
        (const float*)d_in[12], (const float*)d_in[14], (const float*)d_in[16],
        (const float*)d_in[18], (const float*)d_in[20], a1);

    softmax_agg_kernel<72><<<2048, 256, 0, stream>>>(a1, xc, agg1);

    graph1_kernel<<<2048, 64, 0, stream>>>(xc, agg1,
        (const float*)d_in[23], (const float*)d_in[24], out);
}

// Round 12
// 141.769 us; speedup vs baseline: 1.0561x; 1.0561x over previous
//
#include <hip/hip_runtime.h>

typedef __bf16 bf16x8 __attribute__((ext_vector_type(8)));
typedef float f32x4 __attribute__((ext_vector_type(4)));

__device__ __forceinline__ unsigned short f2b(float f) {
    union { float f; unsigned u; } c; c.f = f;
    unsigned u = c.u;
    return (unsigned short)((u + 0x7FFFu + ((u >> 16) & 1u)) >> 16);
}

__device__ __forceinline__ unsigned pack2(float v0, float v1) {
    union { __bf16 h[2]; unsigned u; } c;
    c.h[0] = (__bf16)v0; c.h[1] = (__bf16)v1;
    return c.u;
}

// Direct global->LDS DMA, 16 B per lane. LDS dest is wave-uniform base + lane*16;
// global src is per-lane.
__device__ __forceinline__ void gload_lds16(const unsigned short* g, unsigned short* l) {
    __builtin_amdgcn_global_load_lds(
        (__attribute__((address_space(1))) unsigned int*)(g),
        (__attribute__((address_space(3))) unsigned int*)(l), 16, 0, 0);
}

// Stage one 12-frag (12 KiB) page into LDS: exactly 3 global_load_lds per wave,
// uniform across waves -> a wave-uniform counted vmcnt(3) is legal.
__device__ __forceinline__ void stage_page(const unsigned short* __restrict__ g,
                                           unsigned short* l, int wid, int lane)
{
#pragma unroll
    for (int k = 0; k < 3; ++k) {
        const int idx = wid + k * 4;
        gload_lds16(g + idx * 512 + lane * 8, l + idx * 512);
    }
}

// Triangular entry decode: e in [0, 9216) -> (b, i, j0, offdiag) with j0/32 >= i/32.
__device__ __forceinline__ void decode_entry(int e, int& b, int& i, int& j0, bool& offdiag)
{
    b = e / 1152;
    const int r = e - b * 1152;
    const int tp = r >> 5;                      // tile-pair 0..35 (upper tri of 8x8)
    const int row_in = r & 31;
    int rg = 0, tt = tp;
#pragma unroll 8
    for (;;) { int cnt = 8 - rg; if (tt < cnt) break; tt -= cnt; ++rg; }
    const int cg = rg + tt;
    i = rg * 32 + row_in;
    j0 = cg * 32;
    offdiag = (cg != rg);
}

// Build layer-0 B-frags: B0[t][s] holds |x_i - x_j| transposed (k=fin, col=pos).
// Lane (cl,g): elem e = h0[pos=16t+cl][f=32s+8g+e]; frags fully valid or fully zero
// (CIN multiple of 8).
template<int CIN, int KN0>
__device__ __forceinline__ void build_frags0(const float* __restrict__ xi,
    const float* __restrict__ xj, int cl, int g, bf16x8 (&B0)[2][6])
{
#pragma unroll
    for (int s = 0; s < KN0; ++s) {
        const int f0 = s * 32 + 8 * g;
        const bool valid = f0 < CIN;
        f32x4 xa = {0.f,0.f,0.f,0.f}, xb = {0.f,0.f,0.f,0.f};
        if (valid) { xa = *(const f32x4*)(xi + f0); xb = *(const f32x4*)(xi + f0 + 4); }
#pragma unroll
        for (int t = 0; t < 2; ++t) {
            bf16x8 r;
            if (valid) {
                const float* pj = xj + (16 * t + cl) * CIN + f0;
                f32x4 ja = *(const f32x4*)pj, jb = *(const f32x4*)(pj + 4);
#pragma unroll
                for (int e = 0; e < 4; ++e) {
                    r[e]     = (__bf16)fabsf(xa[e] - ja[e]);
                    r[e + 4] = (__bf16)fabsf(xb[e] - jb[e]);
                }
            } else {
#pragma unroll
                for (int e = 0; e < 8; ++e) r[e] = (__bf16)0.f;
            }
            B0[t][s] = r;
        }
    }
}

// One c-pair (32 output channels x full K) from LDS. Bias is DEFERRED: acc
// zero-init (no load dependency at the head), bias loads issued up front and
// consumed only in the epilogue -- the MFMA loop covers their L2 latency.
// NO setprio: R11 measured it -6% here (lockstep waves within a block -> no
// role diversity to arbitrate; m190 null-signature, not m218b's).
// Shuffle-free repack: next-layer frag CP takes channels from acc tiles
// a=2CP,2CP+1 resident in the SAME lane (tau-permuted downstream weights).
template<int KN, int CP>
__device__ __forceinline__ void run_cpair(const unsigned short* wlds,
    const float* __restrict__ bias, const bf16x8 (&Bc)[2][6], bf16x8 (&Bn)[2][6],
    int lane, int g)
{
    f32x4 bv0 = *(const f32x4*)&bias[(2 * CP + 0) * 16 + 4 * g];
    f32x4 bv1 = *(const f32x4*)&bias[(2 * CP + 1) * 16 + 4 * g];
    f32x4 acc[2][2];                       // [cc][t]
#pragma unroll
    for (int cc = 0; cc < 2; ++cc)
#pragma unroll
        for (int t = 0; t < 2; ++t)
            acc[cc][t] = f32x4{0.f, 0.f, 0.f, 0.f};
#pragma unroll
    for (int s = 0; s < KN; ++s) {
#pragma unroll
        for (int cc = 0; cc < 2; ++cc) {
            bf16x8 w = *(const bf16x8*)&wlds[((cc * KN + s) * 64 + lane) * 8];
#pragma unroll
            for (int t = 0; t < 2; ++t)
                acc[cc][t] = __builtin_amdgcn_mfma_f32_16x16x32_bf16(w, Bc[t][s], acc[cc][t], 0, 0, 0);
        }
    }
#pragma unroll
    for (int t = 0; t < 2; ++t) {
        union { unsigned w[4]; bf16x8 v; } outv;
#pragma unroll
        for (int cc = 0; cc < 2; ++cc) {
            const f32x4 bv = cc ? bv1 : bv0;
#pragma unroll
            for (int m = 0; m < 2; ++m) {
                float v0 = acc[cc][t][2 * m] + bv[2 * m];
                float v1 = acc[cc][t][2 * m + 1] + bv[2 * m + 1];
                v0 = fmaxf(v0, 0.01f * v0);      // LeakyReLU(0.01)
                v1 = fmaxf(v1, 0.01f * v1);
                outv.w[cc * 2 + m] = pack2(v0, v1);
            }
        }
        Bn[t][CP] = outv.v;
    }
}

// adj0 L0 page: 12 frags = 6 c-pairs of KN=1 (c-pair = 1024 elems).
__device__ __forceinline__ void compute_l0_kn1(const unsigned short* cur,
    const float* __restrict__ b0, const bf16x8 (&Ba)[2][6], bf16x8 (&Bb)[2][6],
    int lane, int g)
{
    run_cpair<1, 0>(cur,        b0, Ba, Bb, lane, g);
    run_cpair<1, 1>(cur + 1024, b0, Ba, Bb, lane, g);
    run_cpair<1, 2>(cur + 2048, b0, Ba, Bb, lane, g);
    run_cpair<1, 3>(cur + 3072, b0, Ba, Bb, lane, g);
    run_cpair<1, 4>(cur + 4096, b0, Ba, Bb, lane, g);
    run_cpair<1, 5>(cur + 5120, b0, Ba, Bb, lane, g);
}

// adj1 L0 page P2: 12 frags = 2 c-pairs of KN=3 (c-pair = 3072 elems).
template<int P2>
__device__ __forceinline__ void compute_l0_kn3(const unsigned short* cur,
    const float* __restrict__ b0, const bf16x8 (&Ba)[2][6], bf16x8 (&Bb)[2][6],
    int lane, int g)
{
    run_cpair<3, 2 * P2>    (cur,        b0, Ba, Bb, lane, g);
    run_cpair<3, 2 * P2 + 1>(cur + 3072, b0, Ba, Bb, lane, g);
}

// Counted-vmcnt pipelined phase (T4 pattern, race-free):
//  stage(page p+1)                 -- 3 loads, stays IN FLIGHT under compute
//  vmcnt(3)+barrier                -- page p landed for ALL waves (own 3 allowed out)
//  compute(page p)
//  lgkmcnt(0)+barrier              -- all reads of the other buffer done -> reusable
// No vmcnt(0) drain anywhere in the steady loop. This is the measured-best
// configuration (R9: 141.8 us); R10 page-merge neutral, R11 setprio -6%.
#define PH(OFF, ...) \
    stage_page(wchain + (OFF), nxt, wid, lane); \
    asm volatile("s_waitcnt vmcnt(3)\n\ts_barrier" ::: "memory"); \
    __VA_ARGS__; \
    asm volatile("s_waitcnt lgkmcnt(0)\n\ts_barrier" ::: "memory"); \
    { unsigned short* t_ = cur; cur = nxt; nxt = t_; }

#define PHLAST(...) \
    asm volatile("s_waitcnt vmcnt(0)\n\ts_barrier" ::: "memory"); \
    __VA_ARGS__;

// Fused adjacency MLP exploiting logit symmetry (upper-triangle 32x32 j-tiles,
// off-diagonal entries mirror-write logits[j][i]). Block = 256 threads = 4 waves,
// wave owns ONE entry. Weight chains are consumed as uniform 12 KiB pages
// (adj0: 16, adj1: 18), double-buffered (2 x 12 KiB LDS), counted-vmcnt pipeline.
// (256,3): cap 170 unified regs fits (R8/R9: no spill), 3 blocks/CU = 12 waves/CU.
// Grid 2304 = 256 CU x 3 x 3 rounds, zero tail.
// Register wall note (R7): 2 entries/wave (the only remaining LDS-traffic lever)
// needs ~260 unified regs > the 256 cap at 2 waves/SIMD -> measured spill. This
// structure is at its feasible-design floor.
template<int CIN, int KN0>
__global__ __launch_bounds__(256, 3)
void adj_mlp_kernel(const float* __restrict__ src,
                    const unsigned short* __restrict__ wchain,
                    const unsigned short* __restrict__ w4f,
                    const float* __restrict__ b0, const float* __restrict__ b1,
                    const float* __restrict__ b2, const float* __restrict__ b3,
                    const float* __restrict__ b4,
                    float* __restrict__ logits)
{
    __shared__ unsigned short wbuf0[6144], wbuf1[6144];   // 2 x 12 KiB page buffers
    const int tid = threadIdx.x;
    const int wid = tid >> 6, lane = tid & 63;
    const int cl = lane & 15, g = lane >> 4;

    int b, i, j0; bool offdiag;
    decode_entry(blockIdx.x * 4 + wid, b, i, j0, offdiag);

    const float* xi = src + (b * 256 + i) * CIN;
    const float* xj = src + (b * 256 + j0) * CIN;

    // Prologue: stage page 0; build input frags under the staging latency.
    stage_page(wchain, wbuf0, wid, lane);

    bf16x8 Ba[2][6], Bb[2][6];
    build_frags0<CIN, KN0>(xi, xj, cl, g, Ba);
    unsigned short* cur = wbuf0;
    unsigned short* nxt = wbuf1;

    if constexpr (KN0 == 1) {
        // adj0: 16 pages: [L0 x1][L1 cp0..5][L2 cp0..5][L3 cp0..2]
        PH( 1 * 6144, compute_l0_kn1(cur, b0, Ba, Bb, lane, g))
        PH( 2 * 6144, run_cpair<6, 0>(cur, b1, Bb, Ba, lane, g))
        PH( 3 * 6144, run_cpair<6, 1>(cur, b1, Bb, Ba, lane, g))
        PH( 4 * 6144, run_cpair<6, 2>(cur, b1, Bb, Ba, lane, g))
        PH( 5 * 6144, run_cpair<6, 3>(cur, b1, Bb, Ba, lane, g))
        PH( 6 * 6144, run_cpair<6, 4>(cur, b1, Bb, Ba, lane, g))
        PH( 7 * 6144, run_cpair<6, 5>(cur, b1, Bb, Ba, lane, g))
        PH( 8 * 6144, run_cpair<6, 0>(cur, b2, Ba, Bb, lane, g))
        PH( 9 * 6144, run_cpair<6, 1>(cur, b2, Ba, Bb, lane, g))
        PH(10 * 6144, run_cpair<6, 2>(cur, b2, Ba, Bb, lane, g))
        PH(11 * 6144, run_cpair<6, 3>(cur, b2, Ba, Bb, lane, g))
        PH(12 * 6144, run_cpair<6, 4>(cur, b2, Ba, Bb, lane, g))
        PH(13 * 6144, run_cpair<6, 5>(cur, b2, Ba, Bb, lane, g))
        PH(14 * 6144, run_cpair<6, 0>(cur, b3, Bb, Ba, lane, g))
        PH(15 * 6144, run_cpair<6, 1>(cur, b3, Bb, Ba, lane, g))
        PHLAST(       run_cpair<6, 2>(cur, b3, Bb, Ba, lane, g))
    } else {
        // adj1: 18 pages: [L0 x3][L1 cp0..5][L2 cp0..5][L3 cp0..2]
        PH( 1 * 6144, compute_l0_kn3<0>(cur, b0, Ba, Bb, lane, g))
        PH( 2 * 6144, compute_l0_kn3<1>(cur, b0, Ba, Bb, lane, g))
        PH( 3 * 6144, compute_l0_kn3<2>(cur, b0, Ba, Bb, lane, g))
        PH( 4 * 6144, run_cpair<6, 0>(cur, b1, Bb, Ba, lane, g))
        PH( 5 * 6144, run_cpair<6, 1>(cur, b1, Bb, Ba, lane, g))
        PH( 6 * 6144, run_cpair<6, 2>(cur, b1, Bb, Ba, lane, g))
        PH( 7 * 6144, run_cpair<6, 3>(cur, b1, Bb, Ba, lane, g))
        PH( 8 * 6144, run_cpair<6, 4>(cur, b1, Bb, Ba, lane, g))
        PH( 9 * 6144, run_cpair<6, 5>(cur, b1, Bb, Ba, lane, g))
        PH(10 * 6144, run_cpair<6, 0>(cur, b2, Ba, Bb, lane, g))
        PH(11 * 6144, run_cpair<6, 1>(cur, b2, Ba, Bb, lane, g))
        PH(12 * 6144, run_cpair<6, 2>(cur, b2, Ba, Bb, lane, g))
        PH(13 * 6144, run_cpair<6, 3>(cur, b2, Ba, Bb, lane, g))
        PH(14 * 6144, run_cpair<6, 4>(cur, b2, Ba, Bb, lane, g))
        PH(15 * 6144, run_cpair<6, 5>(cur, b2, Ba, Bb, lane, g))
        PH(16 * 6144, run_cpair<6, 0>(cur, b3, Bb, Ba, lane, g))
        PH(17 * 6144, run_cpair<6, 1>(cur, b3, Bb, Ba, lane, g))
        PHLAST(       run_cpair<6, 2>(cur, b3, Bb, Ba, lane, g))
    }

    // final 96 -> 1: tiny w4 stays in global (L2-hit, 6 loads/wave)
    const float bv4 = b4[0];
#pragma unroll
    for (int t = 0; t < 2; ++t) {
        f32x4 acc = {bv4, bv4, bv4, bv4};
#pragma unroll
        for (int s = 0; s < 3; ++s) {
            bf16x8 w = *(const bf16x8*)(w4f + (s * 64 + lane) * 8);
            acc = __builtin_amdgcn_mfma_f32_16x16x32_bf16(w, Ba[t][s], acc, 0, 0, 0);
        }
        if (g == 0) {
            int j = j0 + 16 * t + cl;
            float lg = acc[0];
            if (j == i) lg -= 1e8f;
            logits[(b * 256 + i) * 256 + j] = lg;
            if (offdiag)
                logits[(b * 256 + j) * 256 + i] = lg;    // symmetric mirror (i != j)
        }
    }
}

// Pre-pack weight matrices (bf16). Same lane<->element map serves A- and B-frags.
// Layers 0-7: conv chains (a0 then a1). Layers 8-9: w4 vectors in row/col 0.
// Layers whose INPUT comes from a previous MFMA layer (1,2,3, 5,6,7, 8,9) use the
// shuffle-free k-permutation tau(s,g,e) = 32s + 16*(e>>2) + 4g + (e&3); layers fed
// by build_frags0 (0, 4) keep the natural order k = 32s + 8g + e.
struct PackPtrs { const float* w[10]; };

__global__ void pack_kernel(PackPtrs pp, unsigned short* __restrict__ dst)
{
    const int K_[10]   = {24, 192, 192, 192, 72, 192, 192, 192, 96, 96};
    const int KN_[10]  = {1, 6, 6, 6, 3, 6, 6, 6, 3, 3};
    const int NO_[10]  = {192, 192, 192, 96, 192, 192, 192, 96, 1, 1};
    const int OFF_[10] = {0, 6144, 43008, 79872, 98304, 116736, 153600, 190464, 208896, 210432};
    const int LEN_[10] = {6144, 36864, 36864, 18432, 18432, 36864, 36864, 18432, 1536, 1536};
    int t = blockIdx.x * 256 + threadIdx.x;   // total threads == 211968 exactly
    int layer = 0, base = 0;
#pragma unroll
    for (int L = 0; L < 10; ++L)
        if (t >= base + LEN_[L]) { base += LEN_[L]; layer = L + 1; }
    if (layer >= 10) return;
    int u = t - base;
    int e = u & 7;
    int lane = (u >> 3) & 63;
    int gg = lane >> 4;
    int KN = KN_[layer];
    int fi = u >> 9;              // frag index = c*KN + s
    int s = fi % KN;
    int c = fi / KN;
    int k;
    if (layer == 0 || layer == 4)
        k = s * 32 + gg * 8 + e;                              // natural (build_frags0 input)
    else
        k = s * 32 + ((e >> 2) << 4) + (gg << 2) + (e & 3);   // tau (MFMA-output input)
    int col = (c << 4) + (lane & 15);
    float v = 0.f;
    if (layer < 8) {
        if (k < K_[layer]) v = pp.w[layer][k * NO_[layer] + col];
    } else {
        if ((lane & 15) == 0) v = pp.w[layer][k];   // k < 96 always
    }
    dst[OFF_[layer] + u] = f2b(v);
}

// Row softmax (in-place on the a-region in d_out) + fused agg[f] = sum_j p[j]*src[b,j,f]
template<int F>
__global__ __launch_bounds__(256)
void softmax_agg_kernel(float* __restrict__ amat, const float* __restrict__ src,
                        float* __restrict__ agg)
{
    __shared__ float pl[256];
    __shared__ float redm[4], reds[4];
    const int row = blockIdx.x;     // b*256 + i
    const int b = row >> 8;
    float* arow = amat + row * 256;
    const int t = threadIdx.x;
    const int lane = t & 63, wid = t >> 6;
    float v = arow[t];
    float m = v;
#pragma unroll
    for (int off = 32; off; off >>= 1) m = fmaxf(m, __shfl_xor(m, off));
    if (lane == 0) redm[wid] = m;
    __syncthreads();
    m = fmaxf(fmaxf(redm[0], redm[1]), fmaxf(redm[2], redm[3]));
    float e = __expf(v - m);
    float sum = e;
#pragma unroll
    for (int off = 32; off; off >>= 1) sum += __shfl_xor(sum, off);
    if (lane == 0) reds[wid] = sum;
    __syncthreads();
    sum = reds[0] + reds[1] + reds[2] + reds[3];
    float p = e / sum;
    arow[t] = p;
    pl[t] = p;
    __syncthreads();
    if (t < F) {
        const float* sb = src + (b * 256) * F + t;
        float acc = 0.f;
#pragma unroll 8
        for (int j = 0; j < 256; ++j)
            acc += pl[j] * sb[j * F];
        agg[row * F + t] = acc;
    }
}

// x1 = leaky([x | agg0] @ g0_w^T + g0_b); xc = [x | x1]
__global__ __launch_bounds__(64)
void graph0_kernel(const float* __restrict__ x, const float* __restrict__ agg0,
                   const float* __restrict__ w, const float* __restrict__ bias,
                   float* __restrict__ xc)
{
    int row = blockIdx.x;
    int t = threadIdx.x;
    const float* xr = x + row * 24;
    const float* ar = agg0 + row * 24;
    if (t < 24) xc[row * 72 + t] = xr[t];
    if (t < 48) {
        float acc = bias[t];
#pragma unroll
        for (int f = 0; f < 24; ++f) acc += xr[f] * w[t * 48 + f];
#pragma unroll
        for (int f = 0; f < 24; ++f) acc += ar[f] * w[t * 48 + 24 + f];
        acc = acc >= 0.f ? acc : 0.01f * acc;
        xc[row * 72 + 24 + t] = acc;
    }
}

// out = [xc | agg1] @ g1_w^T + g1_b   (no activation)
__global__ __launch_bounds__(64)
void graph1_kernel(const float* __restrict__ xc, const float* __restrict__ agg1,
                   const float* __restrict__ w, const float* __restrict__ bias,
                   float* __restrict__ out)
{
    int row = blockIdx.x;
    int t = threadIdx.x;
    float acc = 0.f;
    for (int idx = t; idx < 144; idx += 64) {
        float v = (idx < 72) ? xc[row * 72 + idx] : agg1[row * 72 + idx - 72];
        acc += v * w[idx];
    }
#pragma unroll
    for (int off = 32; off >= 1; off >>= 1) acc += __shfl_xor(acc, off);
    if (t == 0) out[row] = acc + bias[0];
}

extern "C" void kernel_launch(void* const* d_in, const int* in_sizes, int n_in,
                              void* d_out, int out_size, void* d_ws, size_t ws_size,
                              hipStream_t stream)
{
    const float* x = (const float*)d_in[0];
    float* out = (float*)d_out;
    float* a0 = out + 2048;
    float* a1 = a0 + 524288;

    char* ws = (char*)d_ws;
    unsigned short* packed = (unsigned short*)ws;          // 211968 bf16 = 423,936 B
    float* xc   = (float*)(ws + 458752);                   // [2048][72] f32
    float* agg0 = (float*)(ws + 1048576);                  // [2048][24] f32
    float* agg1 = (float*)(ws + 1245184);                  // [2048][72] f32

    PackPtrs pp;
    pp.w[0] = (const float*)d_in[1];   // a0_w0 [24,192]
    pp.w[1] = (const float*)d_in[3];   // a0_w1 [192,192]
    pp.w[2] = (const float*)d_in[5];   // a0_w2
    pp.w[3] = (const float*)d_in[7];   // a0_w3 [192,96]
    pp.w[4] = (const float*)d_in[11];  // a1_w0 [72,192]
    pp.w[5] = (const float*)d_in[13];  // a1_w1
    pp.w[6] = (const float*)d_in[15];  // a1_w2
    pp.w[7] = (const float*)d_in[17];  // a1_w3
    pp.w[8] = (const float*)d_in[9];   // a0_w4 [96,1]
    pp.w[9] = (const float*)d_in[19];  // a1_w4 [96,1]
    pack_kernel<<<828, 256, 0, stream>>>(pp, packed);      // 828*256 == 211968

    adj_mlp_kernel<24, 1><<<2304, 256, 0, stream>>>(
        x, packed, packed + 208896,
        (const float*)d_in[2], (const float*)d_in[4], (const float*)d_in[6],
        (const float*)d_in[8], (const float*)d_in[10], a0);

    softmax_agg_kernel<24><<<2048, 256, 0, stream>>>(a0, x, agg0);

    graph0_kernel<<<2048, 64, 0, stream>>>(x, agg0,
        (const float*)d_in[21], (const float*)d_in[22], xc);

    adj_mlp_kernel<72, 3><<<2304, 256, 0, stream>>>(
        xc, packed + 98304, packed + 210432,
        (const float*)d_in[12], (const float*)d_in[14], (const float*)d_in[16],
        (const float*)d_in[18], (const float*)d_in[20], a1);

    softmax_agg_kernel<72><<<2048, 256, 0, stream>>>(a1, xc, agg1);

    graph1_kernel<<<2048, 64, 0, stream>>>(xc, agg1,
        (const float*)d_in[23], (const float*)d_in[24], out);
}